// Round 1
// baseline (352.432 us; speedup 1.0000x reference)
//
#include <hip/hip_runtime.h>
#include <hip/hip_bf16.h>
#include <cstdint>
#include <cstddef>

// ---------------------------------------------------------------------------
// MAT_31997506355868: fused  QKV-proj -> per-head relu-softmax attention ->
// residual + LayerNorm, plus att column-sum side output.
// B=4, S=1024, NT=1024, HEADS=16 -> 64 "heads" of (1024 x 64) after the
// row-major reshape (head h = contiguous 64-row slab of the 4096x1024 mats).
// scale = 1/sqrt(1024) = 1/32.  softmax(relu(z)): all exp args >= 0, denom
// >= 1024 -> no max subtraction needed.
// ---------------------------------------------------------------------------

typedef short short8 __attribute__((ext_vector_type(8)));
typedef short short4v __attribute__((ext_vector_type(4)));
typedef float f32x4 __attribute__((ext_vector_type(4)));
typedef float float4v __attribute__((ext_vector_type(4)));

#define MFMA16(a, b, c) __builtin_amdgcn_mfma_f32_16x16x32_bf16(a, b, c, 0, 0, 0)

__device__ __forceinline__ short f2bf(float f) {
  union { float f; uint32_t u; } x; x.f = f;
  uint32_t u = x.u + 0x7fffu + ((x.u >> 16) & 1u);  // RNE
  return (short)(u >> 16);
}

// ---- fp32 -> bf16 convert: x (4M) and Wq|Wk|Wv (3x1M) into workspace ------
__global__ __launch_bounds__(256) void convert_kernel(
    const float* __restrict__ x, const float* __restrict__ wq,
    const float* __restrict__ wk, const float* __restrict__ wv,
    short* __restrict__ xb, short* __restrict__ wb) {
  const long XN = 4L * 1024 * 1024, WN = 1024L * 1024;
  long e = (long)(blockIdx.x * blockDim.x + threadIdx.x) * 4;
  const float* src; short* dst;
  if (e < XN)               { src = x  + e;                dst = xb + e; }
  else if (e < XN + WN)     { src = wq + (e - XN);         dst = wb + (e - XN); }
  else if (e < XN + 2 * WN) { src = wk + (e - XN - WN);    dst = wb + (e - XN); }
  else                      { src = wv + (e - XN - 2*WN);  dst = wb + (e - XN); }
  float4v v = *(const float4v*)src;
  short4v o;
  o[0] = f2bf(v[0]); o[1] = f2bf(v[1]); o[2] = f2bf(v[2]); o[3] = f2bf(v[3]);
  *(short4v*)dst = o;
}

// ---- QKV projection: C[m][n] = sum_k xb[m][k]*W[n][k] + b[n] (GEMM-BT) ----
// block = 256 thr (4 waves, 2x2), block tile 128x128, wave tile 64x64 (4x4
// 16x16 tiles), K-step 32 -> one mfma_16x16x32 per tile pair. z-dim picks
// Q/K/V.  Round-1: frags straight from global (L1/L2 reuse), no LDS yet.
__global__ __launch_bounds__(256) void qkv_gemm(
    const short* __restrict__ xb, const short* __restrict__ wb,
    const float* __restrict__ bq, const float* __restrict__ bk,
    const float* __restrict__ bv, short* __restrict__ qb,
    short* __restrict__ kb, short* __restrict__ vb) {
  const int tid = threadIdx.x;
  const int lane = tid & 63, wave = tid >> 6;
  const int lm = lane & 15, quad = lane >> 4;
  const int wy = wave >> 1, wx = wave & 1;
  const int m0 = blockIdx.y * 128 + wy * 64;
  const int n0 = blockIdx.x * 128 + wx * 64;
  const int z = blockIdx.z;
  const short* w = wb + (size_t)z * (1024 * 1024);
  const float* bias = (z == 0) ? bq : (z == 1) ? bk : bv;
  short* out = (z == 0) ? qb : (z == 1) ? kb : vb;

  f32x4 acc[4][4];
#pragma unroll
  for (int i = 0; i < 4; i++)
#pragma unroll
    for (int j = 0; j < 4; j++) acc[i][j] = (f32x4){0.f, 0.f, 0.f, 0.f};

  const short* ap[4]; const short* bp[4];
#pragma unroll
  for (int t = 0; t < 4; t++) {
    ap[t] = xb + (size_t)(m0 + t * 16 + lm) * 1024 + quad * 8;
    bp[t] = w  + (size_t)(n0 + t * 16 + lm) * 1024 + quad * 8;
  }
  for (int k0 = 0; k0 < 1024; k0 += 32) {
    short8 a[4], b[4];
#pragma unroll
    for (int t = 0; t < 4; t++) a[t] = *(const short8*)(ap[t] + k0);
#pragma unroll
    for (int t = 0; t < 4; t++) b[t] = *(const short8*)(bp[t] + k0);
#pragma unroll
    for (int mt = 0; mt < 4; mt++)
#pragma unroll
      for (int nt = 0; nt < 4; nt++)
        acc[mt][nt] = MFMA16(a[mt], b[nt], acc[mt][nt]);
  }
  // epilogue: C/D layout col=lane&15, row=quad*4+reg
#pragma unroll
  for (int nt = 0; nt < 4; nt++) {
    const int n = n0 + nt * 16 + lm;
    const float bn = bias[n];
#pragma unroll
    for (int mt = 0; mt < 4; mt++) {
      const int mb = m0 + mt * 16 + quad * 4;
#pragma unroll
      for (int r = 0; r < 4; r++)
        out[(size_t)(mb + r) * 1024 + n] = f2bf(acc[mt][nt][r] + bn);
    }
  }
}

// ---- fused attention + residual + LayerNorm + colsum ----------------------
// grid: 1024 blocks = 64 heads x 16 row-blocks (64 rows). 4 waves x 16 rows.
// pass 1: denom_i = sum_j exp(relu(z/32)).  pass 2: recompute z, P->LDS,
// PV mfma (V transposed in LDS), colsum_j += r_i*p_ij, then LN epilogue:
// each wave owns exactly one full output row m = 64h + i/16.
#define ATT_SCALE 0.03125f

__global__ __launch_bounds__(256) void attn_kernel(
    const short* __restrict__ qb, const short* __restrict__ kb,
    const short* __restrict__ vb, const float* __restrict__ x,
    const float* __restrict__ gamma, const float* __restrict__ beta,
    float* __restrict__ out1, float* __restrict__ out2) {
  __shared__ __align__(16) short Vt[64 * 40];      // V^T tile: [d][jj], stride 40 (16B-aligned rows, 2-way banks)
  __shared__ __align__(16) short Pw[4][16 * 40];   // per-wave P tile 16x32, stride 40
  __shared__ float colsum[1024];

  const int tid = threadIdx.x;
  const int lane = tid & 63, wave = tid >> 6;
  const int lm = lane & 15, quad = lane >> 4;
  const int h = blockIdx.x >> 4, bb = blockIdx.x & 15;
  const short* Qh = qb + (size_t)h * 65536;
  const short* Kh = kb + (size_t)h * 65536;
  const short* Vh = vb + (size_t)h * 65536;
  const int i0 = bb * 64 + wave * 16;  // this wave's 16 attention rows

  for (int i = tid; i < 1024; i += 256) colsum[i] = 0.f;

  // A-frag layout: A[m=lane&15][k=quad*8+j]
  const short8 aq0 = *(const short8*)(Qh + (size_t)(i0 + lm) * 64 + quad * 8);
  const short8 aq1 = *(const short8*)(Qh + (size_t)(i0 + lm) * 64 + 32 + quad * 8);

  // ---------------- pass 1: denominators ----------------
  f32x4 dacc = {0.f, 0.f, 0.f, 0.f};
  for (int j0 = 0; j0 < 1024; j0 += 16) {
    short8 b0 = *(const short8*)(Kh + (size_t)(j0 + lm) * 64 + quad * 8);
    short8 b1 = *(const short8*)(Kh + (size_t)(j0 + lm) * 64 + 32 + quad * 8);
    f32x4 zz = {0.f, 0.f, 0.f, 0.f};
    zz = MFMA16(aq0, b0, zz);
    zz = MFMA16(aq1, b1, zz);
#pragma unroll
    for (int r = 0; r < 4; r++) dacc[r] += __expf(fmaxf(zz[r] * ATT_SCALE, 0.f));
  }
#pragma unroll
  for (int mk = 1; mk < 16; mk <<= 1) {
#pragma unroll
    for (int r = 0; r < 4; r++) dacc[r] += __shfl_xor(dacc[r], mk, 16);
  }
  float rinv[4];
#pragma unroll
  for (int r = 0; r < 4; r++) rinv[r] = 1.f / dacc[r];  // rows i0+quad*4+r

  // ---------------- pass 2: context + colsum ----------------
  f32x4 accC[4];
#pragma unroll
  for (int t = 0; t < 4; t++) accC[t] = (f32x4){0.f, 0.f, 0.f, 0.f};

  for (int jt = 0; jt < 32; jt++) {
    const int j0 = jt * 32;
    __syncthreads();  // previous Vt fully consumed
    {   // cooperative V-tile load, transposed into LDS: Vt[d][jj]=V[j0+jj][d]
      const int jj = tid >> 3, d0v = (tid & 7) * 8;
      short8 vv = *(const short8*)(Vh + (size_t)(j0 + jj) * 64 + d0v);
#pragma unroll
      for (int u = 0; u < 8; u++) Vt[(d0v + u) * 40 + jj] = vv[u];
    }
#pragma unroll
    for (int sub = 0; sub < 2; sub++) {
      const int j0s = j0 + sub * 16;
      short8 b0 = *(const short8*)(Kh + (size_t)(j0s + lm) * 64 + quad * 8);
      short8 b1 = *(const short8*)(Kh + (size_t)(j0s + lm) * 64 + 32 + quad * 8);
      f32x4 zz = {0.f, 0.f, 0.f, 0.f};
      zz = MFMA16(aq0, b0, zz);
      zz = MFMA16(aq1, b1, zz);
      float p[4], cs = 0.f;
#pragma unroll
      for (int r = 0; r < 4; r++) {
        p[r] = __expf(fmaxf(zz[r] * ATT_SCALE, 0.f));
        cs += p[r] * rinv[r];
      }
      cs += __shfl_xor(cs, 16);  // combine the 4 quads (same column j)
      cs += __shfl_xor(cs, 32);
      if (quad == 0) atomicAdd(&colsum[j0s + lm], cs);
#pragma unroll
      for (int r = 0; r < 4; r++)
        Pw[wave][(quad * 4 + r) * 40 + sub * 16 + lm] = f2bf(p[r]);
    }
    __syncthreads();  // Vt ready; own-wave Pw ordered too
    // PV: A=P (16x32), B=V (32x16 per d-tile)
    short8 apf = *(const short8*)&Pw[wave][lm * 40 + quad * 8];
#pragma unroll
    for (int dt = 0; dt < 4; dt++) {
      short8 bvf = *(const short8*)&Vt[(dt * 16 + lm) * 40 + quad * 8];
      accC[dt] = MFMA16(apf, bvf, accC[dt]);
    }
  }
  __syncthreads();
  for (int i = tid; i < 1024; i += 256)
    atomicAdd(&out2[h * 1024 + i], colsum[i]);

  // ---------------- LN epilogue: wave owns full row m ----------------
  const int m = h * 64 + bb * 4 + wave;
  float hv[4][4], s1 = 0.f, s2 = 0.f;
#pragma unroll
  for (int dt = 0; dt < 4; dt++)
#pragma unroll
    for (int r = 0; r < 4; r++) {
      const int n = (quad * 4 + r) * 64 + dt * 16 + lm;
      const float v = x[(size_t)m * 1024 + n] + accC[dt][r] * rinv[r];
      hv[dt][r] = v; s1 += v; s2 += v * v;
    }
#pragma unroll
  for (int mk = 1; mk < 64; mk <<= 1) {
    s1 += __shfl_xor(s1, mk);
    s2 += __shfl_xor(s2, mk);
  }
  const float mu = s1 * (1.f / 1024.f);
  const float var = s2 * (1.f / 1024.f) - mu * mu;
  const float rstd = rsqrtf(var + 1e-5f);
#pragma unroll
  for (int dt = 0; dt < 4; dt++)
#pragma unroll
    for (int r = 0; r < 4; r++) {
      const int n = (quad * 4 + r) * 64 + dt * 16 + lm;
      out1[(size_t)m * 1024 + n] = (hv[dt][r] - mu) * rstd * gamma[n] + beta[n];
    }
}

extern "C" void kernel_launch(void* const* d_in, const int* in_sizes, int n_in,
                              void* d_out, int out_size, void* d_ws, size_t ws_size,
                              hipStream_t stream) {
  const float* x  = (const float*)d_in[0];
  const float* Wq = (const float*)d_in[1];
  const float* bq = (const float*)d_in[2];
  const float* Wk = (const float*)d_in[3];
  const float* bk = (const float*)d_in[4];
  const float* Wv = (const float*)d_in[5];
  const float* bv = (const float*)d_in[6];
  const float* gamma = (const float*)d_in[7];
  const float* beta  = (const float*)d_in[8];

  float* out1 = (float*)d_out;                       // 4*1024*1024
  float* out2 = out1 + 4L * 1024 * 1024;             // 64*1024 colsums

  short* xb = (short*)d_ws;                          // 4096x1024 bf16
  short* wb = xb + 4L * 1024 * 1024;                 // 3x 1024x1024 bf16
  short* qb = wb + 3L * 1024 * 1024;
  short* kb = qb + 4L * 1024 * 1024;
  short* vb = kb + 4L * 1024 * 1024;

  hipMemsetAsync(out2, 0, 64 * 1024 * sizeof(float), stream);
  convert_kernel<<<7168, 256, 0, stream>>>(x, Wq, Wk, Wv, xb, wb);
  qkv_gemm<<<dim3(8, 32, 3), 256, 0, stream>>>(xb, wb, bq, bk, bv, qb, kb, vb);
  attn_kernel<<<1024, 256, 0, stream>>>(qb, kb, vb, x, gamma, beta, out1, out2);
}

// Round 2
// 280.228 us; speedup vs baseline: 1.2577x; 1.2577x over previous
//
#include <hip/hip_runtime.h>
#include <hip/hip_bf16.h>
#include <cstdint>
#include <cstddef>

// ---------------------------------------------------------------------------
// MAT_31997506355868 round 2.
// Pipeline: convert(fp32->bf16) -> qkv_gemm (m97-style LDS-staged MFMA GEMM)
//   -> vt_kernel (per-head V transpose) -> denom_kernel (QK^T exp-rowsum)
//   -> attn_kernel (barrier-free j-loop: QK^T -> normalized P -> PV + colsum
//      + residual-LayerNorm epilogue).
// Head h = flat reinterpret: rows [64h,64h+64) of the 4096x1024 Q/K/V mats,
// viewed as (1024 x 64).  scale = 1/32; relu-softmax needs no max-subtract.
// ---------------------------------------------------------------------------

typedef short short8 __attribute__((ext_vector_type(8)));
typedef short short4v __attribute__((ext_vector_type(4)));
typedef float f32x4 __attribute__((ext_vector_type(4)));

#define MFMA16(a, b, c) __builtin_amdgcn_mfma_f32_16x16x32_bf16(a, b, c, 0, 0, 0)
#define ATT_SCALE 0.03125f

__device__ __forceinline__ short f2bf(float f) {
  union { float f; uint32_t u; } x; x.f = f;
  uint32_t u = x.u + 0x7fffu + ((x.u >> 16) & 1u);  // RNE
  return (short)(u >> 16);
}

// async global->LDS, 16B per lane; LDS dest = wave-uniform base + lane*16.
#define GLDS16(gp, lp)                                                        \
  __builtin_amdgcn_global_load_lds(                                           \
      (const __attribute__((address_space(1))) void*)(gp),                    \
      (__attribute__((address_space(3))) void*)(lp), 16, 0, 0)

// ---- fp32 -> bf16 convert: x (4M) and Wq|Wk|Wv (3x1M) into workspace ------
__global__ __launch_bounds__(256) void convert_kernel(
    const float* __restrict__ x, const float* __restrict__ wq,
    const float* __restrict__ wk, const float* __restrict__ wv,
    short* __restrict__ xb, short* __restrict__ wb) {
  const long XN = 4L * 1024 * 1024, WN = 1024L * 1024;
  long e = (long)(blockIdx.x * blockDim.x + threadIdx.x) * 4;
  const float* src; short* dst;
  if (e < XN)               { src = x  + e;                dst = xb + e; }
  else if (e < XN + WN)     { src = wq + (e - XN);         dst = wb + (e - XN); }
  else if (e < XN + 2 * WN) { src = wk + (e - XN - WN);    dst = wb + (e - XN); }
  else                      { src = wv + (e - XN - 2*WN);  dst = wb + (e - XN); }
  f32x4 v = *(const f32x4*)src;
  short4v o;
  o[0] = f2bf(v[0]); o[1] = f2bf(v[1]); o[2] = f2bf(v[2]); o[3] = f2bf(v[3]);
  *(short4v*)dst = o;
}

// ---- QKV projection, m97 structure: 128x128 tile, BK=32, async staging ----
// C[m][n] = sum_k xb[m][k]*W[n][k] + b[n].  grid (8,32,3), 256 thr (4 waves
// 2x2, 64x64/wave).  Staging: 2x global_load_lds dwordx4 per thread per
// matrix per K-step; LDS layout = exact lane order (row*64B + colgrp*16B).
__global__ __launch_bounds__(256, 3) void qkv_gemm(
    const short* __restrict__ xb, const short* __restrict__ wb,
    const float* __restrict__ bq, const float* __restrict__ bk,
    const float* __restrict__ bv, short* __restrict__ qb,
    short* __restrict__ kb, short* __restrict__ vb) {
  __shared__ short As[128 * 32];
  __shared__ short Bs[128 * 32];
  const int tid = threadIdx.x;
  const int lane = tid & 63;
  const int lm = lane & 15, quad = lane >> 4;
  const int wave = tid >> 6, wy = wave >> 1, wx = wave & 1;
  const int m0 = blockIdx.y * 128, n0 = blockIdx.x * 128;
  const int z = blockIdx.z;
  const short* w = wb + (size_t)z * (1024 * 1024);
  const float* bias = (z == 0) ? bq : (z == 1) ? bk : bv;
  short* out = (z == 0) ? qb : (z == 1) ? kb : vb;

  // staging source pointers (chunk = it*256+tid; row=chunk/4, colgrp=chunk%4)
  const short* gA0 = xb + (size_t)(m0 + (tid >> 2)) * 1024 + (tid & 3) * 8;
  const short* gA1 = gA0 + 64 * 1024;  // +256 chunks = +64 rows
  const short* gB0 = w  + (size_t)(n0 + (tid >> 2)) * 1024 + (tid & 3) * 8;
  const short* gB1 = gB0 + 64 * 1024;
  short* lA0 = As + tid * 8;          // *8 shorts = *16 bytes
  short* lA1 = As + (tid + 256) * 8;
  short* lB0 = Bs + tid * 8;
  short* lB1 = Bs + (tid + 256) * 8;

  f32x4 acc[4][4];
#pragma unroll
  for (int i = 0; i < 4; i++)
#pragma unroll
    for (int j = 0; j < 4; j++) acc[i][j] = (f32x4){0.f, 0.f, 0.f, 0.f};

  for (int k0 = 0; k0 < 1024; k0 += 32) {
    GLDS16(gA0 + k0, lA0);
    GLDS16(gA1 + k0, lA1);
    GLDS16(gB0 + k0, lB0);
    GLDS16(gB1 + k0, lB1);
    __syncthreads();  // drains vmcnt, LDS tiles ready
    short8 a[4], b[4];
#pragma unroll
    for (int t = 0; t < 4; t++)
      a[t] = *(const short8*)(As + (wy * 64 + t * 16 + lm) * 32 + quad * 8);
#pragma unroll
    for (int t = 0; t < 4; t++)
      b[t] = *(const short8*)(Bs + (wx * 64 + t * 16 + lm) * 32 + quad * 8);
#pragma unroll
    for (int mt = 0; mt < 4; mt++)
#pragma unroll
      for (int nt = 0; nt < 4; nt++)
        acc[mt][nt] = MFMA16(a[mt], b[nt], acc[mt][nt]);
    __syncthreads();  // all reads done before next-iter overwrite
  }
  // epilogue: C/D layout col=lane&15, row=quad*4+reg
#pragma unroll
  for (int nt = 0; nt < 4; nt++) {
    const int n = n0 + wx * 64 + nt * 16 + lm;
    const float bn = bias[n];
#pragma unroll
    for (int mt = 0; mt < 4; mt++) {
      const int mb = m0 + wy * 64 + mt * 16 + quad * 4;
#pragma unroll
      for (int r = 0; r < 4; r++)
        out[(size_t)(mb + r) * 1024 + n] = f2bf(acc[mt][nt][r] + bn);
    }
  }
}

// ---- per-head V transpose: vt[h][d][j] = v[h][j][d] -----------------------
// grid 1024 = 64 heads x 16 j-tiles of 64.  LDS tile 64x64 stride 72
// (144B rows, 16B-aligned -> b128 stores).
__global__ __launch_bounds__(256) void vt_kernel(
    const short* __restrict__ vb, short* __restrict__ vtb) {
  __shared__ short T[64 * 72];
  const int tid = threadIdx.x;
  const int h = blockIdx.x >> 4, j0 = (blockIdx.x & 15) * 64;
  const short* Vh = vb + (size_t)h * 65536;
  short* Vth = vtb + (size_t)h * 65536;
#pragma unroll
  for (int it = 0; it < 2; it++) {
    const int idx = it * 256 + tid;
    const int jj = idx >> 3, dg = idx & 7;
    short8 vv = *(const short8*)(Vh + (size_t)(j0 + jj) * 64 + dg * 8);
    *(short8*)&T[jj * 72 + dg * 8] = vv;
  }
  __syncthreads();
#pragma unroll
  for (int it = 0; it < 2; it++) {
    const int idx = it * 256 + tid;
    const int d = idx >> 3, jg = idx & 7;
    short8 o;
#pragma unroll
    for (int u = 0; u < 8; u++) o[u] = T[(jg * 8 + u) * 72 + d];
    *(short8*)(Vth + (size_t)d * 1024 + j0 + jg * 8) = o;
  }
}

// ---- denominators: denom[h][i] = sum_j exp(relu(q_i.k_j/32)) --------------
// grid (8,64): 128 rows/block, wave owns 32 rows; Q frags loop-invariant in
// regs; j swept 64 at a time: 8 loads -> 16 MFMA -> 32 exp.
__global__ __launch_bounds__(256, 4) void denom_kernel(
    const short* __restrict__ qb, const short* __restrict__ kb,
    float* __restrict__ denomW) {
  const int tid = threadIdx.x;
  const int lane = tid & 63, wave = tid >> 6;
  const int lm = lane & 15, quad = lane >> 4;
  const int h = blockIdx.y;
  const int i0 = blockIdx.x * 128 + wave * 32;
  const short* Qh = qb + (size_t)h * 65536;
  const short* Kh = kb + (size_t)h * 65536;

  short8 aq[2][2];
#pragma unroll
  for (int mt = 0; mt < 2; mt++)
#pragma unroll
    for (int kk = 0; kk < 2; kk++)
      aq[mt][kk] = *(const short8*)(Qh + (size_t)(i0 + mt * 16 + lm) * 64 +
                                    kk * 32 + quad * 8);
  float dsum[2][4];
#pragma unroll
  for (int mt = 0; mt < 2; mt++)
#pragma unroll
    for (int r = 0; r < 4; r++) dsum[mt][r] = 0.f;

  for (int j0 = 0; j0 < 1024; j0 += 64) {
#pragma unroll
    for (int nt = 0; nt < 4; nt++) {
      const short* kr = Kh + (size_t)(j0 + nt * 16 + lm) * 64 + quad * 8;
      short8 bk0 = *(const short8*)kr;
      short8 bk1 = *(const short8*)(kr + 32);
#pragma unroll
      for (int mt = 0; mt < 2; mt++) {
        f32x4 zz = {0.f, 0.f, 0.f, 0.f};
        zz = MFMA16(aq[mt][0], bk0, zz);
        zz = MFMA16(aq[mt][1], bk1, zz);
#pragma unroll
        for (int r = 0; r < 4; r++)
          dsum[mt][r] += __expf(fmaxf(zz[r] * ATT_SCALE, 0.f));
      }
    }
  }
#pragma unroll
  for (int mt = 0; mt < 2; mt++)
#pragma unroll
    for (int r = 0; r < 4; r++) {
      float v = dsum[mt][r];
      v += __shfl_xor(v, 1); v += __shfl_xor(v, 2);
      v += __shfl_xor(v, 4); v += __shfl_xor(v, 8);
      if (lm == 0) denomW[h * 1024 + i0 + mt * 16 + quad * 4 + r] = v;
    }
}

// ---- fused attention: normalized P, PV, colsum, residual+LN ---------------
// grid 1024 = 64 heads x 16 row-blocks; 4 waves x 16 rows.  j-loop has NO
// barriers: K and V^T frags from global, P transposed via same-wave LDS
// (in-order DS pipe), colsum via 2 shuffles + per-wave LDS RMW.
__global__ __launch_bounds__(256, 4) void attn_kernel(
    const short* __restrict__ qb, const short* __restrict__ kb,
    const short* __restrict__ vtb, const float* __restrict__ denomW,
    const float* __restrict__ x, const float* __restrict__ gamma,
    const float* __restrict__ beta, float* __restrict__ out1,
    float* __restrict__ out2) {
  __shared__ short Pw[4][16 * 44];   // stride 44 shorts (88B): 2-way banks, 8B-aligned
  __shared__ float csW[4][1024];     // per-wave colsum accumulators

  const int tid = threadIdx.x;
  const int lane = tid & 63, wave = tid >> 6;
  const int lm = lane & 15, quad = lane >> 4;
  const int h = blockIdx.x >> 4, bb = blockIdx.x & 15;
  const short* Qh = qb + (size_t)h * 65536;
  const short* Kh = kb + (size_t)h * 65536;
  const short* Vth = vtb + (size_t)h * 65536;
  const int i0 = bb * 64 + wave * 16;

  for (int i = tid; i < 4096; i += 256) ((float*)csW)[i] = 0.f;
  __syncthreads();

  // Q A-frags (loop-invariant); reciprocal denominators for own 4 rows
  const short8 aq0 = *(const short8*)(Qh + (size_t)(i0 + lm) * 64 + quad * 8);
  const short8 aq1 = *(const short8*)(Qh + (size_t)(i0 + lm) * 64 + 32 + quad * 8);
  const f32x4 dn = *(const f32x4*)(denomW + h * 1024 + i0 + quad * 4);
  f32x4 rv;
#pragma unroll
  for (int r = 0; r < 4; r++) rv[r] = 1.f / dn[r];

  f32x4 accC[4];
#pragma unroll
  for (int t = 0; t < 4; t++) accC[t] = (f32x4){0.f, 0.f, 0.f, 0.f};

  for (int jt = 0; jt < 32; jt++) {
    const int j0 = jt * 32;
    float p0[4], p1[4], cs0, cs1;
    {  // sub 0: columns j0..j0+15
      const short* kr = Kh + (size_t)(j0 + lm) * 64 + quad * 8;
      short8 b0 = *(const short8*)kr;
      short8 b1 = *(const short8*)(kr + 32);
      f32x4 zz = {0.f, 0.f, 0.f, 0.f};
      zz = MFMA16(aq0, b0, zz);
      zz = MFMA16(aq1, b1, zz);
      cs0 = 0.f;
#pragma unroll
      for (int r = 0; r < 4; r++) {
        p0[r] = __expf(fmaxf(zz[r] * ATT_SCALE, 0.f)) * rv[r];
        cs0 += p0[r];
      }
    }
    {  // sub 1: columns j0+16..j0+31
      const short* kr = Kh + (size_t)(j0 + 16 + lm) * 64 + quad * 8;
      short8 b0 = *(const short8*)kr;
      short8 b1 = *(const short8*)(kr + 32);
      f32x4 zz = {0.f, 0.f, 0.f, 0.f};
      zz = MFMA16(aq0, b0, zz);
      zz = MFMA16(aq1, b1, zz);
      cs1 = 0.f;
#pragma unroll
      for (int r = 0; r < 4; r++) {
        p1[r] = __expf(fmaxf(zz[r] * ATT_SCALE, 0.f)) * rv[r];
        cs1 += p1[r];
      }
    }
    // column sums over this wave's 16 rows (reduce the 4 quads)
    cs0 += __shfl_xor(cs0, 16); cs0 += __shfl_xor(cs0, 32);
    cs1 += __shfl_xor(cs1, 16); cs1 += __shfl_xor(cs1, 32);
    if (quad == 0) {
      csW[wave][j0 + lm] += cs0;
      csW[wave][j0 + 16 + lm] += cs1;
    }
    // P -> LDS (row i, col j-j0); same-wave in-order DS, no barrier needed
#pragma unroll
    for (int r = 0; r < 4; r++) {
      Pw[wave][(quad * 4 + r) * 44 + lm] = f2bf(p0[r]);
      Pw[wave][(quad * 4 + r) * 44 + 16 + lm] = f2bf(p1[r]);
    }
    // PV: A = P (16x32), B = V^T rows (n=d, k=j)
    union { short8 v; short4v half[2]; } apu;
    apu.half[0] = *(const short4v*)&Pw[wave][lm * 44 + quad * 8];
    apu.half[1] = *(const short4v*)&Pw[wave][lm * 44 + quad * 8 + 4];
#pragma unroll
    for (int dt = 0; dt < 4; dt++) {
      short8 bvf = *(const short8*)(Vth + (size_t)(dt * 16 + lm) * 1024 + j0 + quad * 8);
      accC[dt] = MFMA16(apu.v, bvf, accC[dt]);
    }
  }
  __syncthreads();
  for (int j = tid; j < 1024; j += 256)
    atomicAdd(&out2[h * 1024 + j],
              csW[0][j] + csW[1][j] + csW[2][j] + csW[3][j]);

  // LN epilogue: wave owns full output row m (1024 features)
  const int m = h * 64 + bb * 4 + wave;
  float hv[4][4], s1 = 0.f, s2 = 0.f;
#pragma unroll
  for (int dt = 0; dt < 4; dt++)
#pragma unroll
    for (int r = 0; r < 4; r++) {
      const int n = (quad * 4 + r) * 64 + dt * 16 + lm;
      const float v = x[(size_t)m * 1024 + n] + accC[dt][r];
      hv[dt][r] = v; s1 += v; s2 += v * v;
    }
#pragma unroll
  for (int mk = 1; mk < 64; mk <<= 1) {
    s1 += __shfl_xor(s1, mk);
    s2 += __shfl_xor(s2, mk);
  }
  const float mu = s1 * (1.f / 1024.f);
  const float var = s2 * (1.f / 1024.f) - mu * mu;
  const float rstd = rsqrtf(var + 1e-5f);
#pragma unroll
  for (int dt = 0; dt < 4; dt++)
#pragma unroll
    for (int r = 0; r < 4; r++) {
      const int n = (quad * 4 + r) * 64 + dt * 16 + lm;
      out1[(size_t)m * 1024 + n] = (hv[dt][r] - mu) * rstd * gamma[n] + beta[n];
    }
}

extern "C" void kernel_launch(void* const* d_in, const int* in_sizes, int n_in,
                              void* d_out, int out_size, void* d_ws, size_t ws_size,
                              hipStream_t stream) {
  const float* x  = (const float*)d_in[0];
  const float* Wq = (const float*)d_in[1];
  const float* bq = (const float*)d_in[2];
  const float* Wk = (const float*)d_in[3];
  const float* bk = (const float*)d_in[4];
  const float* Wv = (const float*)d_in[5];
  const float* bv = (const float*)d_in[6];
  const float* gamma = (const float*)d_in[7];
  const float* beta  = (const float*)d_in[8];

  float* out1 = (float*)d_out;                       // 4*1024*1024
  float* out2 = out1 + 4L * 1024 * 1024;             // 64*1024 colsums

  short* xb = (short*)d_ws;                          // 4096x1024 bf16
  short* wb = xb + 4L * 1024 * 1024;                 // 3x 1024x1024 bf16
  short* qb = wb + 3L * 1024 * 1024;
  short* kb = qb + 4L * 1024 * 1024;
  short* vb = kb + 4L * 1024 * 1024;
  short* vtb = xb;                                   // reuse xb after qkv_gemm
  float* denomW = (float*)wb;                        // reuse wb after qkv_gemm

  hipMemsetAsync(out2, 0, 64 * 1024 * sizeof(float), stream);
  convert_kernel<<<7168, 256, 0, stream>>>(x, Wq, Wk, Wv, xb, wb);
  qkv_gemm<<<dim3(8, 32, 3), 256, 0, stream>>>(xb, wb, bq, bk, bv, qb, kb, vb);
  vt_kernel<<<1024, 256, 0, stream>>>(vb, vtb);
  denom_kernel<<<dim3(8, 64), 256, 0, stream>>>(qb, kb, denomW);
  attn_kernel<<<1024, 256, 0, stream>>>(qb, kb, vtb, denomW, x, gamma, beta,
                                        out1, out2);
}

// Round 4
// 232.641 us; speedup vs baseline: 1.5149x; 1.2045x over previous
//
#include <hip/hip_runtime.h>
#include <hip/hip_bf16.h>
#include <cstdint>
#include <cstddef>

// ---------------------------------------------------------------------------
// MAT_31997506355868 round 4 (= round 3 structure + vt layout stride fix).
// convert -> qkv_gemm (m97-style, Q pre-scaled by 1/32) -> vt_kernel
// (V^T in frag-major layout) -> denom_kernel -> attn_kernel (LDS-free j-loop
// via the C-layout == K16-B-layout identity: Z^T -> P^T frag -> PV directly).
// Frag-major V^T layout per head: dt-plane (16384 shorts) x j-group g=j/16
// (256 shorts = 64 lanes x 4) x lane*4.  R3 bug: group stride was 1024 ->
// cross-plane/cross-head aliasing + OOB reads of denomW as bf16 (NaN).
// ---------------------------------------------------------------------------

typedef short short8 __attribute__((ext_vector_type(8)));
typedef short short4v __attribute__((ext_vector_type(4)));
typedef float f32x4 __attribute__((ext_vector_type(4)));

#define MFMA32(a, b, c) __builtin_amdgcn_mfma_f32_16x16x32_bf16(a, b, c, 0, 0, 0)
#define MFMA16x16(a, b, c) __builtin_amdgcn_mfma_f32_16x16x16bf16_1k(a, b, c, 0, 0, 0)
#define ATT_SCALE 0.03125f

__device__ __forceinline__ short f2bf(float f) {
  union { float f; uint32_t u; } x; x.f = f;
  uint32_t u = x.u + 0x7fffu + ((x.u >> 16) & 1u);  // RNE
  return (short)(u >> 16);
}

// pack two fp32 -> two bf16 (truncate) in one v_perm_b32
__device__ __forceinline__ uint32_t pk_bf16_trunc(float lo, float hi) {
  return __builtin_amdgcn_perm(__float_as_uint(hi), __float_as_uint(lo),
                               0x07060302u);
}

// async global->LDS, 16B per lane
#define GLDS16(gp, lp)                                                        \
  __builtin_amdgcn_global_load_lds(                                           \
      (const __attribute__((address_space(1))) void*)(gp),                    \
      (__attribute__((address_space(3))) void*)(lp), 16, 0, 0)

// ---- fp32 -> bf16 convert -------------------------------------------------
__global__ __launch_bounds__(256) void convert_kernel(
    const float* __restrict__ x, const float* __restrict__ wq,
    const float* __restrict__ wk, const float* __restrict__ wv,
    short* __restrict__ xb, short* __restrict__ wb) {
  const long XN = 4L * 1024 * 1024, WN = 1024L * 1024;
  long e = (long)(blockIdx.x * blockDim.x + threadIdx.x) * 4;
  const float* src; short* dst;
  if (e < XN)               { src = x  + e;                dst = xb + e; }
  else if (e < XN + WN)     { src = wq + (e - XN);         dst = wb + (e - XN); }
  else if (e < XN + 2 * WN) { src = wk + (e - XN - WN);    dst = wb + (e - XN); }
  else                      { src = wv + (e - XN - 2*WN);  dst = wb + (e - XN); }
  f32x4 v = *(const f32x4*)src;
  short4v o;
  o[0] = f2bf(v[0]); o[1] = f2bf(v[1]); o[2] = f2bf(v[2]); o[3] = f2bf(v[3]);
  *(short4v*)dst = o;
}

// ---- QKV projection (m97 structure).  Q output pre-scaled by 1/32. --------
__global__ __launch_bounds__(256, 3) void qkv_gemm(
    const short* __restrict__ xb, const short* __restrict__ wb,
    const float* __restrict__ bq, const float* __restrict__ bk,
    const float* __restrict__ bv, short* __restrict__ qb,
    short* __restrict__ kb, short* __restrict__ vb) {
  __shared__ short As[128 * 32];
  __shared__ short Bs[128 * 32];
  const int tid = threadIdx.x;
  const int lane = tid & 63;
  const int lm = lane & 15, quad = lane >> 4;
  const int wave = tid >> 6, wy = wave >> 1, wx = wave & 1;
  const int m0 = blockIdx.y * 128, n0 = blockIdx.x * 128;
  const int z = blockIdx.z;
  const short* w = wb + (size_t)z * (1024 * 1024);
  const float* bias = (z == 0) ? bq : (z == 1) ? bk : bv;
  short* out = (z == 0) ? qb : (z == 1) ? kb : vb;
  const float scl = (z == 0) ? ATT_SCALE : 1.0f;

  const short* gA0 = xb + (size_t)(m0 + (tid >> 2)) * 1024 + (tid & 3) * 8;
  const short* gA1 = gA0 + 64 * 1024;
  const short* gB0 = w  + (size_t)(n0 + (tid >> 2)) * 1024 + (tid & 3) * 8;
  const short* gB1 = gB0 + 64 * 1024;
  short* lA0 = As + tid * 8;
  short* lA1 = As + (tid + 256) * 8;
  short* lB0 = Bs + tid * 8;
  short* lB1 = Bs + (tid + 256) * 8;

  f32x4 acc[4][4];
#pragma unroll
  for (int i = 0; i < 4; i++)
#pragma unroll
    for (int j = 0; j < 4; j++) acc[i][j] = (f32x4){0.f, 0.f, 0.f, 0.f};

  for (int k0 = 0; k0 < 1024; k0 += 32) {
    GLDS16(gA0 + k0, lA0);
    GLDS16(gA1 + k0, lA1);
    GLDS16(gB0 + k0, lB0);
    GLDS16(gB1 + k0, lB1);
    __syncthreads();
    short8 a[4], b[4];
#pragma unroll
    for (int t = 0; t < 4; t++)
      a[t] = *(const short8*)(As + (wy * 64 + t * 16 + lm) * 32 + quad * 8);
#pragma unroll
    for (int t = 0; t < 4; t++)
      b[t] = *(const short8*)(Bs + (wx * 64 + t * 16 + lm) * 32 + quad * 8);
#pragma unroll
    for (int mt = 0; mt < 4; mt++)
#pragma unroll
      for (int nt = 0; nt < 4; nt++)
        acc[mt][nt] = MFMA32(a[mt], b[nt], acc[mt][nt]);
    __syncthreads();
  }
#pragma unroll
  for (int nt = 0; nt < 4; nt++) {
    const int n = n0 + wx * 64 + nt * 16 + lm;
    const float bn = bias[n];
#pragma unroll
    for (int mt = 0; mt < 4; mt++) {
      const int mb = m0 + wy * 64 + mt * 16 + quad * 4;
#pragma unroll
      for (int r = 0; r < 4; r++)
        out[(size_t)(mb + r) * 1024 + n] = f2bf((acc[mt][nt][r] + bn) * scl);
    }
  }
}

// ---- V transpose into frag-major layout -----------------------------------
// vtp per head: dt-plane stride 16384, j-group (16 j's) stride 256, lane*4.
// Chunk (h, dt, g, lane=q*16+lm) holds V^T[dt*16+lm][g*16 + q*4 .. +3], so
// attn frag loads are base + lane*8B, perfectly coalesced.
__global__ __launch_bounds__(256) void vt_kernel(
    const short* __restrict__ vb, short* __restrict__ vtp) {
  __shared__ short T[64 * 72];
  const int tid = threadIdx.x;
  const int h = blockIdx.x >> 4, jb = blockIdx.x & 15;  // j-range 64
  const short* Vh = vb + (size_t)h * 65536;
  short* Vo = vtp + (size_t)h * 65536;
#pragma unroll
  for (int it = 0; it < 2; it++) {
    const int idx = it * 256 + tid;
    const int jj = idx >> 3, dg = idx & 7;
    short8 vv = *(const short8*)(Vh + (size_t)(jb * 64 + jj) * 64 + dg * 8);
    *(short8*)&T[jj * 72 + dg * 8] = vv;
  }
  __syncthreads();
#pragma unroll
  for (int it = 0; it < 4; it++) {
    const int c = it * 256 + tid;          // 1024 chunks of 4 shorts
    const int dt = c >> 8, rem = c & 255;
    const int gl = rem >> 6, qlm = rem & 63;
    const int q = qlm >> 4, lmv = qlm & 15;
    const int d = dt * 16 + lmv;
    short4v o;
#pragma unroll
    for (int u = 0; u < 4; u++) o[u] = T[(gl * 16 + q * 4 + u) * 72 + d];
    *(short4v*)(Vo + dt * 16384 + (size_t)(jb * 4 + gl) * 256 + qlm * 4) = o;
  }
}

// ---- denominators: denom[h][i] = sum_j exp(relu(q_i.k_j)) (q pre-scaled) --
__global__ __launch_bounds__(256, 4) void denom_kernel(
    const short* __restrict__ qb, const short* __restrict__ kb,
    float* __restrict__ denomW) {
  const int tid = threadIdx.x;
  const int lane = tid & 63, wave = tid >> 6;
  const int lm = lane & 15, quad = lane >> 4;
  const int h = blockIdx.y;
  const int i0 = blockIdx.x * 128 + wave * 32;
  const short* Qh = qb + (size_t)h * 65536;
  const short* Kh = kb + (size_t)h * 65536;

  short8 aq[2][2];
#pragma unroll
  for (int mt = 0; mt < 2; mt++)
#pragma unroll
    for (int kk = 0; kk < 2; kk++)
      aq[mt][kk] = *(const short8*)(Qh + (size_t)(i0 + mt * 16 + lm) * 64 +
                                    kk * 32 + quad * 8);
  float dsum[2][4];
#pragma unroll
  for (int mt = 0; mt < 2; mt++)
#pragma unroll
    for (int r = 0; r < 4; r++) dsum[mt][r] = 0.f;

  for (int j0 = 0; j0 < 1024; j0 += 64) {
#pragma unroll
    for (int nt = 0; nt < 4; nt++) {
      const short* kr = Kh + (size_t)(j0 + nt * 16 + lm) * 64 + quad * 8;
      short8 bk0 = *(const short8*)kr;
      short8 bk1 = *(const short8*)(kr + 32);
#pragma unroll
      for (int mt = 0; mt < 2; mt++) {
        f32x4 zz = {0.f, 0.f, 0.f, 0.f};
        zz = MFMA32(aq[mt][0], bk0, zz);
        zz = MFMA32(aq[mt][1], bk1, zz);
#pragma unroll
        for (int r = 0; r < 4; r++)
          dsum[mt][r] += __expf(fmaxf(zz[r], 0.f));
      }
    }
  }
#pragma unroll
  for (int mt = 0; mt < 2; mt++)
#pragma unroll
    for (int r = 0; r < 4; r++) {
      float v = dsum[mt][r];
      v += __shfl_xor(v, 1); v += __shfl_xor(v, 2);
      v += __shfl_xor(v, 4); v += __shfl_xor(v, 8);
      if (lm == 0) denomW[h * 1024 + i0 + mt * 16 + quad * 4 + r] = v;
    }
}

// ---- fused attention: LDS-free j-loop -------------------------------------
// grid 512 = 64 heads x 8 blocks of 128 rows; wave owns 32 rows (2 tiles).
// Z^T = MFMA(A=K,B=Q) -> lane holds P^T[j=quad*4+r][i=lane&15], which IS the
// B-operand layout of mfma_16x16x16 -> PV with A=V^T frag, no transpose.
__global__ __launch_bounds__(256, 2) void attn_kernel(
    const short* __restrict__ qb, const short* __restrict__ kb,
    const short* __restrict__ vtp, const float* __restrict__ denomW,
    const float* __restrict__ x, const float* __restrict__ gamma,
    const float* __restrict__ beta, float* __restrict__ out1,
    float* __restrict__ out2) {
  __shared__ float csW[4][1024];

  const int tid = threadIdx.x;
  const int lane = tid & 63, wave = tid >> 6;
  const int lm = lane & 15, quad = lane >> 4;
  const int h = blockIdx.x >> 3, bb = blockIdx.x & 7;
  const short* Qh = qb + (size_t)h * 65536;
  const short* Kh = kb + (size_t)h * 65536;
  const short* Vp = vtp + (size_t)h * 65536;
  const int i0 = bb * 128 + wave * 32;   // tiles at i0 and i0+16

  for (int i = tid; i < 4096; i += 256) ((float*)csW)[i] = 0.f;
  __syncthreads();

  const short8 qA0 = *(const short8*)(Qh + (size_t)(i0 + lm) * 64 + quad * 8);
  const short8 qA1 = *(const short8*)(Qh + (size_t)(i0 + lm) * 64 + 32 + quad * 8);
  const short8 qB0 = *(const short8*)(Qh + (size_t)(i0 + 16 + lm) * 64 + quad * 8);
  const short8 qB1 = *(const short8*)(Qh + (size_t)(i0 + 16 + lm) * 64 + 32 + quad * 8);
  const float rvA = 1.f / denomW[h * 1024 + i0 + lm];
  const float rvB = 1.f / denomW[h * 1024 + i0 + 16 + lm];

  f32x4 accA[4], accB[4];
#pragma unroll
  for (int t = 0; t < 4; t++) {
    accA[t] = (f32x4){0.f, 0.f, 0.f, 0.f};
    accB[t] = (f32x4){0.f, 0.f, 0.f, 0.f};
  }

#pragma unroll 4
  for (int j0 = 0; j0 < 1024; j0 += 16) {
    const short* kr = Kh + (size_t)(j0 + lm) * 64 + quad * 8;
    const short8 kf0 = *(const short8*)kr;
    const short8 kf1 = *(const short8*)(kr + 32);
    f32x4 zA = {0.f, 0.f, 0.f, 0.f};
    zA = MFMA32(kf0, qA0, zA);
    zA = MFMA32(kf1, qA1, zA);
    f32x4 zB = {0.f, 0.f, 0.f, 0.f};
    zB = MFMA32(kf0, qB0, zB);
    zB = MFMA32(kf1, qB1, zB);
    float pA[4], pB[4], cs[4];
#pragma unroll
    for (int r = 0; r < 4; r++) {
      pA[r] = __expf(fmaxf(zA[r], 0.f)) * rvA;
      pB[r] = __expf(fmaxf(zB[r], 0.f)) * rvB;
      cs[r] = pA[r] + pB[r];
    }
    // colsum over the wave's 32 i-rows: reduce across lm within each quad
#pragma unroll
    for (int mk = 1; mk < 16; mk <<= 1)
#pragma unroll
      for (int r = 0; r < 4; r++) cs[r] += __shfl_xor(cs[r], mk);
    if (lm == 0) {
#pragma unroll
      for (int r = 0; r < 4; r++) csW[wave][j0 + quad * 4 + r] += cs[r];
    }
    // pack P^T frags (truncating bf16)
    union { uint32_t u[2]; short4v s; } puA, puB;
    puA.u[0] = pk_bf16_trunc(pA[0], pA[1]);
    puA.u[1] = pk_bf16_trunc(pA[2], pA[3]);
    puB.u[0] = pk_bf16_trunc(pB[0], pB[1]);
    puB.u[1] = pk_bf16_trunc(pB[2], pB[3]);
    // PV: A = V^T frag (coalesced frag-major), B = P^T frag
    const short* vbase = Vp + (j0 >> 4) * 256 + lane * 4;
#pragma unroll
    for (int dt = 0; dt < 4; dt++) {
      const short4v vtf = *(const short4v*)(vbase + dt * 16384);
      accA[dt] = MFMA16x16(vtf, puA.s, accA[dt]);
      accB[dt] = MFMA16x16(vtf, puB.s, accB[dt]);
    }
  }
  __syncthreads();
  for (int j = tid; j < 1024; j += 256)
    atomicAdd(&out2[h * 1024 + j],
              csW[0][j] + csW[1][j] + csW[2][j] + csW[3][j]);

  // ---- LN epilogue: ctx^T layout -> n = lm*64 + dt*16 + quad*4 + r --------
  const int mA = h * 64 + bb * 8 + wave * 2;  // tile A row; tile B = mA+1
  const int nb = lm * 64 + quad * 4;
#pragma unroll
  for (int tile = 0; tile < 2; tile++) {
    const int m = mA + tile;
    const f32x4* accT = tile ? accB : accA;
    const float* xr = x + (size_t)m * 1024;
    float hv[4][4], s1 = 0.f, s2 = 0.f;
#pragma unroll
    for (int dt = 0; dt < 4; dt++) {
      f32x4 xv = *(const f32x4*)(xr + nb + dt * 16);
#pragma unroll
      for (int r = 0; r < 4; r++) {
        const float v = xv[r] + accT[dt][r];
        hv[dt][r] = v; s1 += v; s2 += v * v;
      }
    }
#pragma unroll
    for (int mk = 1; mk < 64; mk <<= 1) {
      s1 += __shfl_xor(s1, mk);
      s2 += __shfl_xor(s2, mk);
    }
    const float mu = s1 * (1.f / 1024.f);
    const float var = s2 * (1.f / 1024.f) - mu * mu;
    const float rstd = rsqrtf(var + 1e-5f);
    float* orow = out1 + (size_t)m * 1024;
#pragma unroll
    for (int dt = 0; dt < 4; dt++) {
      f32x4 gv = *(const f32x4*)(gamma + nb + dt * 16);
      f32x4 bv2 = *(const f32x4*)(beta + nb + dt * 16);
      f32x4 ov;
#pragma unroll
      for (int r = 0; r < 4; r++)
        ov[r] = (hv[dt][r] - mu) * rstd * gv[r] + bv2[r];
      *(f32x4*)(orow + nb + dt * 16) = ov;
    }
  }
}

extern "C" void kernel_launch(void* const* d_in, const int* in_sizes, int n_in,
                              void* d_out, int out_size, void* d_ws, size_t ws_size,
                              hipStream_t stream) {
  const float* x  = (const float*)d_in[0];
  const float* Wq = (const float*)d_in[1];
  const float* bq = (const float*)d_in[2];
  const float* Wk = (const float*)d_in[3];
  const float* bk = (const float*)d_in[4];
  const float* Wv = (const float*)d_in[5];
  const float* bv = (const float*)d_in[6];
  const float* gamma = (const float*)d_in[7];
  const float* beta  = (const float*)d_in[8];

  float* out1 = (float*)d_out;                       // 4*1024*1024
  float* out2 = out1 + 4L * 1024 * 1024;             // 64*1024 colsums

  short* xb = (short*)d_ws;                          // 4096x1024 bf16
  short* wb = xb + 4L * 1024 * 1024;                 // 3x 1024x1024 bf16
  short* qb = wb + 3L * 1024 * 1024;
  short* kb = qb + 4L * 1024 * 1024;
  short* vb = kb + 4L * 1024 * 1024;
  short* vtp = xb;                                   // reuse xb after qkv_gemm
  float* denomW = (float*)wb;                        // reuse wb after qkv_gemm

  hipMemsetAsync(out2, 0, 64 * 1024 * sizeof(float), stream);
  convert_kernel<<<7168, 256, 0, stream>>>(x, Wq, Wk, Wv, xb, wb);
  qkv_gemm<<<dim3(8, 32, 3), 256, 0, stream>>>(xb, wb, bq, bk, bv, qb, kb, vb);
  vt_kernel<<<1024, 256, 0, stream>>>(vb, vtp);
  denom_kernel<<<dim3(8, 64), 256, 0, stream>>>(qb, kb, denomW);
  attn_kernel<<<512, 256, 0, stream>>>(qb, kb, vtp, denomW, x, gamma, beta,
                                       out1, out2);
}